// Round 9
// baseline (204.888 us; speedup 1.0000x reference)
//
#include <hip/hip_runtime.h>
#include <math.h>

typedef unsigned short u16;
typedef unsigned int   u32;
typedef unsigned long long u64;
typedef short  v8s __attribute__((ext_vector_type(8)));   // 8 bf16 = 4 VGPRs (MFMA A/B frag)
typedef float  v4f __attribute__((ext_vector_type(4)));   // MFMA C/D frag

constexpr int NB=2048, NN=60, DD=6, AF=37, BFD=6, HH=128, CC=12;
constexpr int T  = 1024;        // 16 waves/block; 2 blocks/CU (LDS-capped) -> 32 waves/CU
constexpr int NW = T/64;        // 16
constexpr int FASTR = 168;      // A-buffer row stride (bf16); rows 0..63 = hi, 64..127 = lo
constexpr int XSTR  = 132;      // X-buffer row stride (fp32)
constexpr int ASTR  = 40;       // padded atom-staging row stride (fp32); cols 37..39 = 0
constexpr int KS1 = 2;          // conv1: K=43 -> 64
constexpr int KS2 = 5;          // conv2/gout: K=134 -> 160
constexpr int MAXP = 32;

// d_ws layout: 1KB fragment blocks per (d, ntile, kstep); hi table, lo mirror at LO_OFF.
constexpr int W1T_UNITS = 6*8*KS1;   // 96
constexpr int W2T_UNITS = 6*8*KS2;   // 240
constexpr int WOT_UNITS = 8*KS2;     // 40
constexpr int TOT_UNITS = W1T_UNITS + W2T_UNITS + WOT_UNITS;   // 376 x2 = 770 KB
constexpr int W2T_OFF = W1T_UNITS*512;
constexpr int WOT_OFF = (W1T_UNITS+W2T_UNITS)*512;
constexpr int LO_OFF  = TOT_UNITS*512;

__device__ __forceinline__ u16 f2bf(float f) {         // RNE fp32->bf16 (prep path)
  u32 u = __float_as_uint(f);
  return (u16)((u + 0x7FFFu + ((u >> 16) & 1u)) >> 16);
}
__device__ __forceinline__ float bf2f(u16 h) { return __uint_as_float((u32)h << 16); }

// split pair (a,b): hi = RNE bf16 via HW v_cvt_pk_bf16_f32 (1 op for both);
// lo = TRUNCATED residual bf16 packed via v_perm_b32 (1 op for both).
__device__ __forceinline__ void split2(float a, float b, u32& hi, u32& lo) {
  u32 h;
  asm("v_cvt_pk_bf16_f32 %0, %1, %2" : "=v"(h) : "v"(a), "v"(b));
  float ra = a - __uint_as_float(h << 16);          // a - bf16(a)
  float rb = b - __uint_as_float(h & 0xffff0000u);  // b - bf16(b)
  hi = h;
  lo = __builtin_amdgcn_perm(__float_as_uint(rb), __float_as_uint(ra), 0x07060302u);
}
__device__ __forceinline__ void split8(const float* v, uint4& hi, uint4& lo) {
  split2(v[0], v[1], hi.x, lo.x); split2(v[2], v[3], hi.y, lo.y);
  split2(v[4], v[5], hi.z, lo.z); split2(v[6], v[7], hi.w, lo.w);
}
__device__ __forceinline__ void split4(const float* v, uint2& hi, uint2& lo) {
  split2(v[0], v[1], hi.x, lo.x); split2(v[2], v[3], hi.y, lo.y);
}
__device__ __forceinline__ float fast_tanh(float x) {
  float e = __expf(2.f * x);            // inf-safe
  return 1.f - 2.f / (e + 1.f);
}

// ---- prep: 753 blocks x 256 threads, one element/thread ----
__global__ __launch_bounds__(256) void prep_kernel(
    const float* __restrict__ W1, const float* __restrict__ W2,
    const float* __restrict__ Wo, u16* __restrict__ ws)
{
  int tid = blockIdx.x*256 + threadIdx.x;
  if (tid >= TOT_UNITS*512) return;
  int unit = tid >> 9, idx = tid & 511;
  int lane = idx >> 3, j = idx & 7;
  int n16 = lane & 15, q = lane >> 4;
  const float* src; int K, nt, ks;
  if (unit < W1T_UNITS) {
    int d = unit / 16, rem = unit % 16; nt = rem >> 1; ks = rem & 1;
    src = W1 + (size_t)d*43*128; K = 43;
  } else if (unit < W1T_UNITS + W2T_UNITS) {
    int u = unit - W1T_UNITS; int d = u / 40, rem = u % 40; nt = rem / 5; ks = rem % 5;
    src = W2 + (size_t)d*134*128; K = 134;
  } else {
    int u = unit - (W1T_UNITS + W2T_UNITS); nt = u / 5; ks = u % 5;
    src = Wo; K = 134;
  }
  int k = ks*32 + q*8 + j, n = nt*16 + n16;
  float v = (k < K) ? src[(size_t)k*128 + n] : 0.f;
  u16 hi = f2bf(v);
  u16 lo = (u16)(__float_as_uint(v - bf2f(hi)) >> 16);
  ws[(size_t)unit*512 + lane*8 + j] = hi;
  ws[(size_t)(LO_OFF + unit*512) + lane*8 + j] = lo;
}

// ---- conv via bf16x3 MFMA. Work unit = (pair, nt-PAIR) with ks-INTERCHANGED
// loop: per ks, A-frags loaded ONCE (2 b128) and reused for both nt (B loads
// inner, from L2). Halves conv A-traffic through the shared per-CU LDS pipe —
// the hand-counted bottleneck (~61% busy). Live set ~40 VGPR at unroll 1
// (held-A variants spill: R2/R4). ----
template<int KSTEPS>
__device__ __forceinline__ void conv_mfma(
    const u16* __restrict__ wsW, const float* __restrict__ bias,
    const u16* sFA, float* sXout,
    const int* sSorted, const int* sDeg,
    const int* sPairD, const int* sPairM,
    const int* sPairLo, const int* sPairHi, int nP,
    int wv, int lane)
{
  const int n16 = lane & 15, q = lane >> 4;
  for (int u = wv; u < nP*4; u += NW) {
    const int p = u >> 2, nt0 = (u & 3) * 2;
    const int d = sPairD[p], mt = sPairM[p];
    const int row = mt*16 + n16;
    const int h0 = nt0*16 + n16, h1 = h0 + 16;
    const int rbase = mt*16 + q*4;
    int nodes[4];
    #pragma unroll
    for (int r = 0; r < 4; ++r) nodes[r] = sSorted[rbase + r];
    if (d == 6) {                    // ref zeroes deg-6; degrees are 1..5 in practice
      #pragma unroll
      for (int r = 0; r < 4; ++r)
        if (nodes[r] >= 0 && sDeg[nodes[r]] == 6) {
          sXout[nodes[r]*XSTR + h0] = 0.f;
          sXout[nodes[r]*XSTR + h1] = 0.f;
        }
      continue;
    }
    const int lo_r = sPairLo[p], hi_r = sPairHi[p];
    const float bb0 = bias[d*128 + h0], bb1 = bias[d*128 + h1];
    const u16* baseA  = &sFA[row*FASTR];
    const u16* baseAl = &sFA[(64 + row)*FASTR];
    const u16* baseB0 = wsW + ((size_t)((d*8 + nt0)*KSTEPS))*512 + lane*8;
    const u16* baseB1 = baseB0 + (size_t)KSTEPS*512;
    v4f acc0 = {0.f, 0.f, 0.f, 0.f};
    v4f acc1 = {0.f, 0.f, 0.f, 0.f};
    #pragma unroll 1
    for (int ks = 0; ks < KSTEPS; ++ks) {
      v8s ah = *(const v8s*)(baseA + ks*32 + q*8);
      v8s al = *(const v8s*)(baseAl + ks*32 + q*8);
      v8s bh0 = *(const v8s*)(baseB0 + ks*512);
      v8s bl0 = *(const v8s*)(baseB0 + LO_OFF + ks*512);
      v8s bh1 = *(const v8s*)(baseB1 + ks*512);
      v8s bl1 = *(const v8s*)(baseB1 + LO_OFF + ks*512);
      acc0 = __builtin_amdgcn_mfma_f32_16x16x32_bf16(ah, bh0, acc0, 0, 0, 0);
      acc0 = __builtin_amdgcn_mfma_f32_16x16x32_bf16(al, bh0, acc0, 0, 0, 0);
      acc0 = __builtin_amdgcn_mfma_f32_16x16x32_bf16(ah, bl0, acc0, 0, 0, 0);
      acc1 = __builtin_amdgcn_mfma_f32_16x16x32_bf16(ah, bh1, acc1, 0, 0, 0);
      acc1 = __builtin_amdgcn_mfma_f32_16x16x32_bf16(al, bh1, acc1, 0, 0, 0);
      acc1 = __builtin_amdgcn_mfma_f32_16x16x32_bf16(ah, bl1, acc1, 0, 0, 0);
    }
    #pragma unroll
    for (int r = 0; r < 4; ++r) {
      const int rgl = rbase + r;
      if (rgl >= lo_r && rgl < hi_r) {        // row in this pair's degree run
        sXout[nodes[r]*XSTR + h0] = fmaxf(acc0[r] + bb0, 0.f);
        sXout[nodes[r]*XSTR + h1] = fmaxf(acc1[r] + bb1, 0.f);
      }
    }
  }
}

// 16 waves/block x 2 blocks/CU (LDS-capped) = 32 waves/CU = 8 waves/SIMD (HW max).
// VGPR must stay <=64.
__global__ __launch_bounds__(T, 8) void ngfp_kernel(
    const float* __restrict__ atoms, const float* __restrict__ bonds,
    const int*   __restrict__ edges,
    const float* __restrict__ b1, const float* __restrict__ b2,
    const float* __restrict__ bo,
    const float* __restrict__ Wfc, const float* __restrict__ bfc,
    const u16*   __restrict__ ws,
    float* __restrict__ out)
{
  __shared__ u16   sFA[128*FASTR];   // 43008 B — A-tiles hi (rows 0..63) + lo (64..127)
  __shared__ float sXa[NN*XSTR];     // 31680 B — atom staging / X1/X2/x3 (fp32)
  __shared__ float sBsum[NN*BFD];
  __shared__ int  sEdges[NN*DD];
  __shared__ int  sDeg[NN];
  __shared__ int  sSorted[64];
  __shared__ int  sPairD[MAXP];
  __shared__ int  sPairM[MAXP];
  __shared__ int  sPairLo[MAXP];
  __shared__ int  sPairHi[MAXP];
  __shared__ int  sNP;
  __shared__ float sPart[4*HH];      // four mt-quarters per h at the new P8 split
  __shared__ float sRed[96];
  // total ~81.0 KB -> still 2 blocks/CU (<= 81920), 32 waves/CU

  float* const sAtoms = sXa;   // stride-40 zero-padded staging, dead once A1 built

  const int b = blockIdx.x;
  const int t = threadIdx.x;
  const int wv = t >> 6;
  const int lane = t & 63;

  // ---- P0: stage edges, atoms (stride-40, cols 37..39 zeroed), bond-sums ----
  for (int i = t; i < NN*DD; i += T) sEdges[i] = edges[b*NN*DD + i];
  for (int i = t; i < NN*ASTR; i += T) {
    int n = i / ASTR, f = i - n*ASTR;
    sAtoms[i] = (f < AF) ? atoms[b*NN*AF + n*AF + f] : 0.f;
  }
  for (int i = t; i < NN*BFD; i += T) {
    int n = i / BFD, f = i - n*BFD;
    const float* bp = bonds + ((size_t)(b*NN + n)*DD)*BFD + f;
    float s = 0.f;
    #pragma unroll
    for (int d = 0; d < DD; ++d) s += bp[d*BFD];
    sBsum[i] = s;
  }
  __syncthreads();

  // ---- P0b: wave-0 ballot sort: degree, counting sort, pair list w/ run bounds ----
  if (wv == 0) {
    const int n = lane;                 // 0..63
    int dg = 7;                          // sentinel for pad lanes
    if (n < NN) {
      dg = 0;
      #pragma unroll
      for (int d = 0; d < DD; ++d) dg += (sEdges[n*DD + d] != -1) ? 1 : 0;
      sDeg[n] = dg;
    } else {
      sSorted[n] = -1;                   // pad entries 60..63
    }
    const u64 below = (lane == 63) ? ~0ull >> 1 : ((1ull << lane) - 1);
    int rs = 0, np = 0;
    #pragma unroll 1
    for (int d = 0; d < 7; ++d) {
      u64 m = __ballot(dg == d);
      int cnt = (int)__popcll(m);
      if (dg == d) sSorted[rs + (int)__popcll(m & below)] = n;
      if (lane == 0 && cnt > 0) {
        const int r1 = rs + cnt;
        for (int mt = rs >> 4; mt < ((r1 + 15) >> 4); ++mt) {
          sPairD[np] = d; sPairM[np] = mt;
          sPairLo[np] = rs; sPairHi[np] = r1; ++np;
        }
      }
      rs += cnt;
    }
    if (lane == 0) sNP = np;
  }
  __syncthreads();
  const int nP = sNP;

  // ---- P1: A1 build — VECTOR float4 gathers from the stride-40 padded staging.
  // c<=9: self float4 + deg neighbor float4 (pads are zero so k=37..39 pick up
  // harmless zeros, then overwritten). c==9 patches k=37..39 = bsum[0..2];
  // c==10 is bsum[3..5]; c>=11 zeros. ----
  {
    const int row = t >> 4, c = t & 15;
    const int node = sSorted[row];
    float acc[4] = {0,0,0,0};
    if (node >= 0) {
      const int dg = sDeg[node];
      if (c < 10) {
        float4 a = *(const float4*)(&sAtoms[node*ASTR + c*4]);
        #pragma unroll 1
        for (int d = 0; d < dg; ++d) {
          const int e = sEdges[node*DD + d];
          float4 u = *(const float4*)(&sAtoms[e*ASTR + c*4]);
          a.x += u.x; a.y += u.y; a.z += u.z; a.w += u.w;
        }
        acc[0]=a.x; acc[1]=a.y; acc[2]=a.z; acc[3]=a.w;
        if (c == 9) {                    // k=37,38,39 are self-only bsum
          acc[1] = sBsum[node*BFD + 0];
          acc[2] = sBsum[node*BFD + 1];
          acc[3] = sBsum[node*BFD + 2];
        }
      } else if (c == 10) {              // k=40,41,42 = bsum[3..5]; k=43 pad
        acc[0] = sBsum[node*BFD + 3];
        acc[1] = sBsum[node*BFD + 4];
        acc[2] = sBsum[node*BFD + 5];
      }
    }
    uint2 hi, lo; split4(acc, hi, lo);
    *(uint2*)(&sFA[row*FASTR + c*4]) = hi;
    *(uint2*)(&sFA[(64 + row)*FASTR + c*4]) = lo;
  }
  __syncthreads();

  // ---- P2: conv1 MFMA -> X1 (sXa fp32) ----
  conv_mfma<KS1>(ws, b1, sFA, sXa, sSorted, sDeg, sPairD, sPairM, sPairLo, sPairHi,
                 nP, wv, lane);
  __syncthreads();

  // ---- P3: pool1 IN PLACE: X2 = max(self, nbrs)(X1) * (deg>0); degree-bounded ----
  {
    float4 m[2];
    #pragma unroll
    for (int j = 0; j < 2; ++j) {
      int idx = t + j*T;
      if (idx < NN*32) {
        int n = idx >> 5, c = idx & 31;
        float4 v = {0.f, 0.f, 0.f, 0.f};
        const int dg = sDeg[n];
        if (dg > 0) {
          v = *(const float4*)(&sXa[n*XSTR + c*4]);
          #pragma unroll 1
          for (int d = 0; d < dg; ++d) {
            const int e = sEdges[n*DD + d];
            float4 u = *(const float4*)(&sXa[e*XSTR + c*4]);
            v.x = fmaxf(v.x, u.x); v.y = fmaxf(v.y, u.y);
            v.z = fmaxf(v.z, u.z); v.w = fmaxf(v.w, u.w);
          }
        }
        m[j] = v;
      }
    }
    __syncthreads();
    #pragma unroll
    for (int j = 0; j < 2; ++j) {
      int idx = t + j*T;
      if (idx < NN*32) {
        int n = idx >> 5, c = idx & 31;
        *(float4*)(&sXa[n*XSTR + c*4]) = m[j];
      }
    }
  }
  __syncthreads();

  // ---- P4: A2 build — degree-bounded sums; (c, c+16) col pairing ----
  {
    const int row = t >> 4, c = t & 15;
    const int node = sSorted[row];
    float accA[4] = {0,0,0,0}, accB[4] = {0,0,0,0};
    if (node >= 0) {
      const int dg = sDeg[node];
      float4 a = *(const float4*)(&sXa[node*XSTR + c*4]);
      float4 bq = *(const float4*)(&sXa[node*XSTR + 64 + c*4]);
      #pragma unroll 1
      for (int d = 0; d < dg; ++d) {
        const int e = sEdges[node*DD + d];
        float4 u0 = *(const float4*)(&sXa[e*XSTR + c*4]);
        float4 u1 = *(const float4*)(&sXa[e*XSTR + 64 + c*4]);
        a.x+=u0.x; a.y+=u0.y; a.z+=u0.z; a.w+=u0.w;
        bq.x+=u1.x; bq.y+=u1.y; bq.z+=u1.z; bq.w+=u1.w;
      }
      accA[0]=a.x; accA[1]=a.y; accA[2]=a.z; accA[3]=a.w;
      accB[0]=bq.x; accB[1]=bq.y; accB[2]=bq.z; accB[3]=bq.w;
    }
    uint2 hiA, loA, hiB, loB;
    split4(accA, hiA, loA); split4(accB, hiB, loB);
    *(uint2*)(&sFA[row*FASTR + c*4]) = hiA;
    *(uint2*)(&sFA[row*FASTR + 64 + c*4]) = hiB;
    *(uint2*)(&sFA[(64 + row)*FASTR + c*4]) = loA;
    *(uint2*)(&sFA[(64 + row)*FASTR + 64 + c*4]) = loB;
  }
  // K-tail k=128..159 (bsum | zeros) — written ONCE; P6 leaves it untouched so
  // A3 (gout) reuses it (bsum is layer-invariant).
  if (t < 256) {
    int row = t >> 2, part = t & 3;
    uint4 hi = {0,0,0,0}, lo = {0,0,0,0};
    if (part == 0) {
      int node = sSorted[row];
      float acc[8] = {0,0,0,0,0,0,0,0};
      if (node >= 0) {
        #pragma unroll
        for (int j = 0; j < BFD; ++j) acc[j] = sBsum[node*BFD + j];
      }
      split8(acc, hi, lo);
    }
    *(uint4*)(&sFA[row*FASTR + 128 + part*8]) = hi;
    *(uint4*)(&sFA[(64 + row)*FASTR + 128 + part*8]) = lo;
  }
  __syncthreads();

  // ---- P5: conv2 MFMA -> x3 (sXa) ----
  conv_mfma<KS2>(ws + W2T_OFF, b2, sFA, sXa, sSorted, sDeg, sPairD, sPairM,
                 sPairLo, sPairHi, nP, wv, lane);
  __syncthreads();

  // ---- P6+P7 FUSED: x4 = max(self,nbrs)(x3)*(deg>0) -> A3 hi/lo; degree-
  // bounded loop + (c, c+16) pairing ----
  {
    const int row = t >> 4, c = t & 15;
    const int node = sSorted[row];
    float accA[4] = {0,0,0,0}, accB[4] = {0,0,0,0};
    if (node >= 0) {
      const int dg = sDeg[node];
      if (dg > 0) {
        float4 a = *(const float4*)(&sXa[node*XSTR + c*4]);
        float4 bq = *(const float4*)(&sXa[node*XSTR + 64 + c*4]);
        #pragma unroll 1
        for (int d = 0; d < dg; ++d) {
          const int e = sEdges[node*DD + d];
          float4 u0 = *(const float4*)(&sXa[e*XSTR + c*4]);
          float4 u1 = *(const float4*)(&sXa[e*XSTR + 64 + c*4]);
          a.x = fmaxf(a.x, u0.x); a.y = fmaxf(a.y, u0.y);
          a.z = fmaxf(a.z, u0.z); a.w = fmaxf(a.w, u0.w);
          bq.x = fmaxf(bq.x, u1.x); bq.y = fmaxf(bq.y, u1.y);
          bq.z = fmaxf(bq.z, u1.z); bq.w = fmaxf(bq.w, u1.w);
        }
        accA[0]=a.x; accA[1]=a.y; accA[2]=a.z; accA[3]=a.w;
        accB[0]=bq.x; accB[1]=bq.y; accB[2]=bq.z; accB[3]=bq.w;
      }
    }
    uint2 hiA, loA, hiB, loB;
    split4(accA, hiA, loA); split4(accB, hiB, loB);
    *(uint2*)(&sFA[row*FASTR + c*4]) = hiA;
    *(uint2*)(&sFA[row*FASTR + 64 + c*4]) = hiB;
    *(uint2*)(&sFA[(64 + row)*FASTR + c*4]) = loA;
    *(uint2*)(&sFA[(64 + row)*FASTR + 64 + c*4]) = loB;
  }
  __syncthreads();

  // ---- P8: gout MFMA — (quarter-mt x nt-pair) decomposition: wave (mt=wv&3,
  // ntp=wv>>2) loads A for ONE mt (2 b128/ks) and reuses it for two nt (B from
  // L2 doubles — cheap). Halves P8's LDS A-traffic vs the half x nt split. ----
  {
    const int mt = wv & 3, ntp = wv >> 2;
    const int n16 = lane & 15, q = lane >> 4;
    const int h0 = ntp*32 + n16, h1 = h0 + 16;   // nt0=2*ntp, nt1=2*ntp+1
    const float bb0 = bo[h0], bb1 = bo[h1];
    const int row = mt*16 + n16;
    const u16* baseA  = &sFA[row*FASTR];
    const u16* baseAl = &sFA[(64 + row)*FASTR];
    const u16* baseB0 = ws + WOT_OFF + ((size_t)(2*ntp*KS2))*512 + lane*8;
    const u16* baseB1 = baseB0 + (size_t)KS2*512;
    v4f acc0 = {0.f, 0.f, 0.f, 0.f};
    v4f acc1 = {0.f, 0.f, 0.f, 0.f};
    #pragma unroll 1
    for (int ks = 0; ks < KS2; ++ks) {
      v8s ah = *(const v8s*)(baseA + ks*32 + q*8);
      v8s al = *(const v8s*)(baseAl + ks*32 + q*8);
      v8s bh0 = *(const v8s*)(baseB0 + ks*512);
      v8s bl0 = *(const v8s*)(baseB0 + LO_OFF + ks*512);
      v8s bh1 = *(const v8s*)(baseB1 + ks*512);
      v8s bl1 = *(const v8s*)(baseB1 + LO_OFF + ks*512);
      acc0 = __builtin_amdgcn_mfma_f32_16x16x32_bf16(ah, bh0, acc0, 0, 0, 0);
      acc0 = __builtin_amdgcn_mfma_f32_16x16x32_bf16(al, bh0, acc0, 0, 0, 0);
      acc0 = __builtin_amdgcn_mfma_f32_16x16x32_bf16(ah, bl0, acc0, 0, 0, 0);
      acc1 = __builtin_amdgcn_mfma_f32_16x16x32_bf16(ah, bh1, acc1, 0, 0, 0);
      acc1 = __builtin_amdgcn_mfma_f32_16x16x32_bf16(al, bh1, acc1, 0, 0, 0);
      acc1 = __builtin_amdgcn_mfma_f32_16x16x32_bf16(ah, bl1, acc1, 0, 0, 0);
    }
    float part0 = 0.f, part1 = 0.f;
    #pragma unroll
    for (int r = 0; r < 4; ++r) {
      int node = sSorted[mt*16 + q*4 + r];
      if (node >= 0 && sDeg[node] > 0) {
        part0 += fast_tanh(acc0[r] + bb0);
        part1 += fast_tanh(acc1[r] + bb1);
      }
    }
    part0 += __shfl_xor(part0, 16);
    part0 += __shfl_xor(part0, 32);
    part1 += __shfl_xor(part1, 16);
    part1 += __shfl_xor(part1, 32);
    if (lane < 16) {
      sPart[mt*HH + h0] = part0;
      sPart[mt*HH + h1] = part1;
    }
  }
  __syncthreads();

  // ---- P9: final FC + sigmoid (96 threads, 16 FMAs each over 4 quarters) ----
  if (t < 96) {
    const int c = t >> 3, s = t & 7;
    float acc = 0.f;
    #pragma unroll
    for (int i = 0; i < 16; ++i) {
      int ii = s*16 + i;
      float v = sPart[ii] + sPart[HH + ii] + sPart[2*HH + ii] + sPart[3*HH + ii];
      acc = fmaf(v, Wfc[ii*CC + c], acc);
    }
    sRed[t] = acc;
  }
  __syncthreads();
  if (t < CC) {
    float acc = bfc[t];
    #pragma unroll
    for (int s = 0; s < 8; ++s) acc += sRed[t*8 + s];
    out[b*CC + t] = 1.f / (1.f + __expf(-acc));
  }
}

extern "C" void kernel_launch(void* const* d_in, const int* in_sizes, int n_in,
                              void* d_out, int out_size, void* d_ws, size_t ws_size,
                              hipStream_t stream) {
  const float* atoms = (const float*)d_in[0];
  const float* bonds = (const float*)d_in[1];
  const int*   edges = (const int*)d_in[2];
  const float* W1  = (const float*)d_in[3];
  const float* b1  = (const float*)d_in[4];
  const float* W2  = (const float*)d_in[5];
  const float* b2  = (const float*)d_in[6];
  const float* Wo  = (const float*)d_in[7];
  const float* bo  = (const float*)d_in[8];
  const float* Wfc = (const float*)d_in[9];
  const float* bfc = (const float*)d_in[10];
  float* out = (float*)d_out;
  u16* ws = (u16*)d_ws;

  prep_kernel<<<(TOT_UNITS*512 + 255)/256, 256, 0, stream>>>(W1, W2, Wo, ws);
  ngfp_kernel<<<NB, T, 0, stream>>>(atoms, bonds, edges, b1, b2, bo, Wfc, bfc, ws, out);
}

// Round 10
// 200.931 us; speedup vs baseline: 1.0197x; 1.0197x over previous
//
#include <hip/hip_runtime.h>
#include <math.h>

typedef unsigned short u16;
typedef unsigned int   u32;
typedef unsigned long long u64;
typedef short  v8s __attribute__((ext_vector_type(8)));   // 8 bf16 = 4 VGPRs (MFMA A/B frag)
typedef float  v4f __attribute__((ext_vector_type(4)));   // MFMA C/D frag

constexpr int NB=2048, NN=60, DD=6, AF=37, BFD=6, HH=128, CC=12;
constexpr int T  = 1024;        // 16 waves/block; 2 blocks/CU (LDS-capped) -> 32 waves/CU
constexpr int NW = T/64;        // 16
constexpr int FASTR = 168;      // A-buffer row stride (bf16); rows 0..63 = hi, 64..127 = lo
constexpr int XSTR  = 132;      // X-buffer row stride (fp32)
constexpr int ASTR  = 40;       // padded atom-staging row stride (fp32); cols 37..39 = 0
constexpr int KS1 = 2;          // conv1: K=43 -> 64
constexpr int KS2 = 5;          // conv2/gout: K=134 -> 160
constexpr int MAXP = 32;

// d_ws layout: 1KB fragment blocks per (d, ntile, kstep); hi table, lo mirror at LO_OFF.
constexpr int W1T_UNITS = 6*8*KS1;   // 96
constexpr int W2T_UNITS = 6*8*KS2;   // 240
constexpr int WOT_UNITS = 8*KS2;     // 40
constexpr int TOT_UNITS = W1T_UNITS + W2T_UNITS + WOT_UNITS;   // 376 x2 = 770 KB
constexpr int W2T_OFF = W1T_UNITS*512;
constexpr int WOT_OFF = (W1T_UNITS+W2T_UNITS)*512;
constexpr int LO_OFF  = TOT_UNITS*512;

__device__ __forceinline__ u16 f2bf(float f) {         // RNE fp32->bf16 (prep path)
  u32 u = __float_as_uint(f);
  return (u16)((u + 0x7FFFu + ((u >> 16) & 1u)) >> 16);
}
__device__ __forceinline__ float bf2f(u16 h) { return __uint_as_float((u32)h << 16); }

// split pair (a,b): hi = RNE bf16 via HW v_cvt_pk_bf16_f32 (1 op for both);
// lo = TRUNCATED residual bf16 packed via v_perm_b32 (1 op for both).
__device__ __forceinline__ void split2(float a, float b, u32& hi, u32& lo) {
  u32 h;
  asm("v_cvt_pk_bf16_f32 %0, %1, %2" : "=v"(h) : "v"(a), "v"(b));
  float ra = a - __uint_as_float(h << 16);          // a - bf16(a)
  float rb = b - __uint_as_float(h & 0xffff0000u);  // b - bf16(b)
  hi = h;
  lo = __builtin_amdgcn_perm(__float_as_uint(rb), __float_as_uint(ra), 0x07060302u);
}
__device__ __forceinline__ void split8(const float* v, uint4& hi, uint4& lo) {
  split2(v[0], v[1], hi.x, lo.x); split2(v[2], v[3], hi.y, lo.y);
  split2(v[4], v[5], hi.z, lo.z); split2(v[6], v[7], hi.w, lo.w);
}
__device__ __forceinline__ void split4(const float* v, uint2& hi, uint2& lo) {
  split2(v[0], v[1], hi.x, lo.x); split2(v[2], v[3], hi.y, lo.y);
}
__device__ __forceinline__ float fast_tanh(float x) {
  float e = __expf(2.f * x);            // inf-safe
  return 1.f - 2.f / (e + 1.f);
}

// ---- prep: 753 blocks x 256 threads, one element/thread ----
__global__ __launch_bounds__(256) void prep_kernel(
    const float* __restrict__ W1, const float* __restrict__ W2,
    const float* __restrict__ Wo, u16* __restrict__ ws)
{
  int tid = blockIdx.x*256 + threadIdx.x;
  if (tid >= TOT_UNITS*512) return;
  int unit = tid >> 9, idx = tid & 511;
  int lane = idx >> 3, j = idx & 7;
  int n16 = lane & 15, q = lane >> 4;
  const float* src; int K, nt, ks;
  if (unit < W1T_UNITS) {
    int d = unit / 16, rem = unit % 16; nt = rem >> 1; ks = rem & 1;
    src = W1 + (size_t)d*43*128; K = 43;
  } else if (unit < W1T_UNITS + W2T_UNITS) {
    int u = unit - W1T_UNITS; int d = u / 40, rem = u % 40; nt = rem / 5; ks = rem % 5;
    src = W2 + (size_t)d*134*128; K = 134;
  } else {
    int u = unit - (W1T_UNITS + W2T_UNITS); nt = u / 5; ks = u % 5;
    src = Wo; K = 134;
  }
  int k = ks*32 + q*8 + j, n = nt*16 + n16;
  float v = (k < K) ? src[(size_t)k*128 + n] : 0.f;
  u16 hi = f2bf(v);
  u16 lo = (u16)(__float_as_uint(v - bf2f(hi)) >> 16);
  ws[(size_t)unit*512 + lane*8 + j] = hi;
  ws[(size_t)(LO_OFF + unit*512) + lane*8 + j] = lo;
}

// ---- conv via bf16x3 MFMA. Work unit = (pair, SINGLE nt) — R8-verified best
// balance (exactly 3 units/wave at nP=6). unroll-2 window on ks (R7-verified:
// compiler overlaps two iterations' loads within the 64-VGPR budget; manual
// rotation/batching spill — R2/R4). ----
template<int KSTEPS>
__device__ __forceinline__ void conv_mfma(
    const u16* __restrict__ wsW, const float* __restrict__ bias,
    const u16* sFA, float* sXout,
    const int* sSorted, const int* sDeg,
    const int* sPairD, const int* sPairM,
    const int* sPairLo, const int* sPairHi, int nP,
    int wv, int lane)
{
  const int n16 = lane & 15, q = lane >> 4;
  for (int u = wv; u < nP*8; u += NW) {
    const int p = u >> 3, nt = u & 7;
    const int d = sPairD[p], mt = sPairM[p];
    const int row = mt*16 + n16;
    const int h = nt*16 + n16;
    const int rbase = mt*16 + q*4;
    int nodes[4];
    #pragma unroll
    for (int r = 0; r < 4; ++r) nodes[r] = sSorted[rbase + r];
    if (d == 6) {                    // ref zeroes deg-6; degrees are 1..5 in practice
      #pragma unroll
      for (int r = 0; r < 4; ++r)
        if (nodes[r] >= 0 && sDeg[nodes[r]] == 6) sXout[nodes[r]*XSTR + h] = 0.f;
      continue;
    }
    const int lo_r = sPairLo[p], hi_r = sPairHi[p];
    const float bb = bias[d*128 + h];          // hoisted: issue early, consume late
    const u16* baseA  = &sFA[row*FASTR];
    const u16* baseAl = &sFA[(64 + row)*FASTR];
    const u16* baseB  = wsW + ((size_t)((d*8 + nt)*KSTEPS))*512 + lane*8;
    v4f acc = {0.f, 0.f, 0.f, 0.f};
    #pragma unroll 2
    for (int ks = 0; ks < KSTEPS; ++ks) {
      v8s ah = *(const v8s*)(baseA + ks*32 + q*8);
      v8s al = *(const v8s*)(baseAl + ks*32 + q*8);
      v8s bh = *(const v8s*)(baseB + ks*512);
      v8s bl = *(const v8s*)(baseB + LO_OFF + ks*512);
      acc = __builtin_amdgcn_mfma_f32_16x16x32_bf16(ah, bh, acc, 0, 0, 0);
      acc = __builtin_amdgcn_mfma_f32_16x16x32_bf16(al, bh, acc, 0, 0, 0);
      acc = __builtin_amdgcn_mfma_f32_16x16x32_bf16(ah, bl, acc, 0, 0, 0);
    }
    #pragma unroll
    for (int r = 0; r < 4; ++r) {
      const int rgl = rbase + r;
      if (rgl >= lo_r && rgl < hi_r)          // row in this pair's degree run
        sXout[nodes[r]*XSTR + h] = fmaxf(acc[r] + bb, 0.f);
    }
  }
}

// 16 waves/block x 2 blocks/CU (LDS-capped) = 32 waves/CU = 8 waves/SIMD (HW max).
// VGPR must stay <=64.
__global__ __launch_bounds__(T, 8) void ngfp_kernel(
    const float* __restrict__ atoms, const float* __restrict__ bonds,
    const int*   __restrict__ edges,
    const float* __restrict__ b1, const float* __restrict__ b2,
    const float* __restrict__ bo,
    const float* __restrict__ Wfc, const float* __restrict__ bfc,
    const u16*   __restrict__ ws,
    float* __restrict__ out)
{
  __shared__ u16   sFA[128*FASTR];   // 43008 B — A-tiles hi (rows 0..63) + lo (64..127)
  __shared__ float sXa[NN*XSTR];     // 31680 B — atom staging / X1/X2/x3 (fp32)
  __shared__ float sBsum[NN*BFD];
  __shared__ int  sEdges[NN*DD];
  __shared__ int  sDeg[NN];
  __shared__ int  sSorted[64];
  __shared__ int  sPairD[MAXP];
  __shared__ int  sPairM[MAXP];
  __shared__ int  sPairLo[MAXP];
  __shared__ int  sPairHi[MAXP];
  __shared__ int  sNP;
  __shared__ float sPart[4*HH];      // four mt-quarters per h at the P8 split
  __shared__ float sRed[96];
  // total ~81.4 KB -> still 2 blocks/CU (<= 81920), 32 waves/CU

  float* const sAtoms = sXa;   // stride-40 zero-padded staging, dead once A1 built

  const int b = blockIdx.x;
  const int t = threadIdx.x;
  const int wv = t >> 6;
  const int lane = t & 63;

  // ---- P0 || P0b OVERLAPPED: wave 0 reads edges from GLOBAL and runs the
  // ballot sort (deg/sorted/pair-list) while waves 1..15 stage edges, atoms
  // (stride-40, cols 37..39 zeroed) and bond-sums to LDS. Disjoint LDS writes;
  // ONE barrier instead of two, and the serial sort leaves the critical path. ----
  if (wv == 0) {
    const int n = lane;                 // 0..63
    int dg = 7;                          // sentinel for pad lanes
    if (n < NN) {
      dg = 0;
      const int* ep = edges + b*NN*DD + n*DD;
      #pragma unroll
      for (int d = 0; d < DD; ++d) dg += (ep[d] != -1) ? 1 : 0;
      sDeg[n] = dg;
    } else {
      sSorted[n] = -1;                   // pad entries 60..63
    }
    const u64 below = (lane == 63) ? ~0ull >> 1 : ((1ull << lane) - 1);
    int rs = 0, np = 0;
    #pragma unroll 1
    for (int d = 0; d < 7; ++d) {
      u64 m = __ballot(dg == d);
      int cnt = (int)__popcll(m);
      if (dg == d) sSorted[rs + (int)__popcll(m & below)] = n;
      if (lane == 0 && cnt > 0) {
        const int r1 = rs + cnt;
        for (int mt = rs >> 4; mt < ((r1 + 15) >> 4); ++mt) {
          sPairD[np] = d; sPairM[np] = mt;
          sPairLo[np] = rs; sPairHi[np] = r1; ++np;
        }
      }
      rs += cnt;
    }
    if (lane == 0) sNP = np;
  } else {
    const int tt = t - 64;               // 0..959 over 15 waves
    for (int i = tt; i < NN*DD; i += T - 64) sEdges[i] = edges[b*NN*DD + i];
    for (int i = tt; i < NN*ASTR; i += T - 64) {
      int n = i / ASTR, f = i - n*ASTR;
      sAtoms[i] = (f < AF) ? atoms[b*NN*AF + n*AF + f] : 0.f;
    }
    for (int i = tt; i < NN*BFD; i += T - 64) {
      int n = i / BFD, f = i - n*BFD;
      const float* bp = bonds + ((size_t)(b*NN + n)*DD)*BFD + f;
      float s = 0.f;
      #pragma unroll
      for (int d = 0; d < DD; ++d) s += bp[d*BFD];
      sBsum[i] = s;
    }
  }
  __syncthreads();
  const int nP = sNP;

  // ---- P1: A1 build — VECTOR float4 gathers from the stride-40 padded staging.
  // c<=9: self float4 + deg neighbor float4 (pads are zero so k=37..39 pick up
  // harmless zeros, then overwritten). c==9 patches k=37..39 = bsum[0..2];
  // c==10 is bsum[3..5]; c>=11 zeros. ----
  {
    const int row = t >> 4, c = t & 15;
    const int node = sSorted[row];
    float acc[4] = {0,0,0,0};
    if (node >= 0) {
      const int dg = sDeg[node];
      if (c < 10) {
        float4 a = *(const float4*)(&sAtoms[node*ASTR + c*4]);
        #pragma unroll 1
        for (int d = 0; d < dg; ++d) {
          const int e = sEdges[node*DD + d];
          float4 u = *(const float4*)(&sAtoms[e*ASTR + c*4]);
          a.x += u.x; a.y += u.y; a.z += u.z; a.w += u.w;
        }
        acc[0]=a.x; acc[1]=a.y; acc[2]=a.z; acc[3]=a.w;
        if (c == 9) {                    // k=37,38,39 are self-only bsum
          acc[1] = sBsum[node*BFD + 0];
          acc[2] = sBsum[node*BFD + 1];
          acc[3] = sBsum[node*BFD + 2];
        }
      } else if (c == 10) {              // k=40,41,42 = bsum[3..5]; k=43 pad
        acc[0] = sBsum[node*BFD + 3];
        acc[1] = sBsum[node*BFD + 4];
        acc[2] = sBsum[node*BFD + 5];
      }
    }
    uint2 hi, lo; split4(acc, hi, lo);
    *(uint2*)(&sFA[row*FASTR + c*4]) = hi;
    *(uint2*)(&sFA[(64 + row)*FASTR + c*4]) = lo;
  }
  __syncthreads();

  // ---- P2: conv1 MFMA -> X1 (sXa fp32) ----
  conv_mfma<KS1>(ws, b1, sFA, sXa, sSorted, sDeg, sPairD, sPairM, sPairLo, sPairHi,
                 nP, wv, lane);
  __syncthreads();

  // ---- P3: pool1 IN PLACE: X2 = max(self, nbrs)(X1) * (deg>0); degree-bounded ----
  {
    float4 m[2];
    #pragma unroll
    for (int j = 0; j < 2; ++j) {
      int idx = t + j*T;
      if (idx < NN*32) {
        int n = idx >> 5, c = idx & 31;
        float4 v = {0.f, 0.f, 0.f, 0.f};
        const int dg = sDeg[n];
        if (dg > 0) {
          v = *(const float4*)(&sXa[n*XSTR + c*4]);
          #pragma unroll 1
          for (int d = 0; d < dg; ++d) {
            const int e = sEdges[n*DD + d];
            float4 u = *(const float4*)(&sXa[e*XSTR + c*4]);
            v.x = fmaxf(v.x, u.x); v.y = fmaxf(v.y, u.y);
            v.z = fmaxf(v.z, u.z); v.w = fmaxf(v.w, u.w);
          }
        }
        m[j] = v;
      }
    }
    __syncthreads();
    #pragma unroll
    for (int j = 0; j < 2; ++j) {
      int idx = t + j*T;
      if (idx < NN*32) {
        int n = idx >> 5, c = idx & 31;
        *(float4*)(&sXa[n*XSTR + c*4]) = m[j];
      }
    }
  }
  __syncthreads();

  // ---- P4: A2 build — degree-bounded sums; (c, c+16) col pairing ----
  {
    const int row = t >> 4, c = t & 15;
    const int node = sSorted[row];
    float accA[4] = {0,0,0,0}, accB[4] = {0,0,0,0};
    if (node >= 0) {
      const int dg = sDeg[node];
      float4 a = *(const float4*)(&sXa[node*XSTR + c*4]);
      float4 bq = *(const float4*)(&sXa[node*XSTR + 64 + c*4]);
      #pragma unroll 1
      for (int d = 0; d < dg; ++d) {
        const int e = sEdges[node*DD + d];
        float4 u0 = *(const float4*)(&sXa[e*XSTR + c*4]);
        float4 u1 = *(const float4*)(&sXa[e*XSTR + 64 + c*4]);
        a.x+=u0.x; a.y+=u0.y; a.z+=u0.z; a.w+=u0.w;
        bq.x+=u1.x; bq.y+=u1.y; bq.z+=u1.z; bq.w+=u1.w;
      }
      accA[0]=a.x; accA[1]=a.y; accA[2]=a.z; accA[3]=a.w;
      accB[0]=bq.x; accB[1]=bq.y; accB[2]=bq.z; accB[3]=bq.w;
    }
    uint2 hiA, loA, hiB, loB;
    split4(accA, hiA, loA); split4(accB, hiB, loB);
    *(uint2*)(&sFA[row*FASTR + c*4]) = hiA;
    *(uint2*)(&sFA[row*FASTR + 64 + c*4]) = hiB;
    *(uint2*)(&sFA[(64 + row)*FASTR + c*4]) = loA;
    *(uint2*)(&sFA[(64 + row)*FASTR + 64 + c*4]) = loB;
  }
  // K-tail k=128..159 (bsum | zeros) — written ONCE; P6 leaves it untouched so
  // A3 (gout) reuses it (bsum is layer-invariant).
  if (t < 256) {
    int row = t >> 2, part = t & 3;
    uint4 hi = {0,0,0,0}, lo = {0,0,0,0};
    if (part == 0) {
      int node = sSorted[row];
      float acc[8] = {0,0,0,0,0,0,0,0};
      if (node >= 0) {
        #pragma unroll
        for (int j = 0; j < BFD; ++j) acc[j] = sBsum[node*BFD + j];
      }
      split8(acc, hi, lo);
    }
    *(uint4*)(&sFA[row*FASTR + 128 + part*8]) = hi;
    *(uint4*)(&sFA[(64 + row)*FASTR + 128 + part*8]) = lo;
  }
  __syncthreads();

  // ---- P5: conv2 MFMA -> x3 (sXa) ----
  conv_mfma<KS2>(ws + W2T_OFF, b2, sFA, sXa, sSorted, sDeg, sPairD, sPairM,
                 sPairLo, sPairHi, nP, wv, lane);
  __syncthreads();

  // ---- P6+P7 FUSED: x4 = max(self,nbrs)(x3)*(deg>0) -> A3 hi/lo; degree-
  // bounded loop + (c, c+16) pairing ----
  {
    const int row = t >> 4, c = t & 15;
    const int node = sSorted[row];
    float accA[4] = {0,0,0,0}, accB[4] = {0,0,0,0};
    if (node >= 0) {
      const int dg = sDeg[node];
      if (dg > 0) {
        float4 a = *(const float4*)(&sXa[node*XSTR + c*4]);
        float4 bq = *(const float4*)(&sXa[node*XSTR + 64 + c*4]);
        #pragma unroll 1
        for (int d = 0; d < dg; ++d) {
          const int e = sEdges[node*DD + d];
          float4 u0 = *(const float4*)(&sXa[e*XSTR + c*4]);
          float4 u1 = *(const float4*)(&sXa[e*XSTR + 64 + c*4]);
          a.x = fmaxf(a.x, u0.x); a.y = fmaxf(a.y, u0.y);
          a.z = fmaxf(a.z, u0.z); a.w = fmaxf(a.w, u0.w);
          bq.x = fmaxf(bq.x, u1.x); bq.y = fmaxf(bq.y, u1.y);
          bq.z = fmaxf(bq.z, u1.z); bq.w = fmaxf(bq.w, u1.w);
        }
        accA[0]=a.x; accA[1]=a.y; accA[2]=a.z; accA[3]=a.w;
        accB[0]=bq.x; accB[1]=bq.y; accB[2]=bq.z; accB[3]=bq.w;
      }
    }
    uint2 hiA, loA, hiB, loB;
    split4(accA, hiA, loA); split4(accB, hiB, loB);
    *(uint2*)(&sFA[row*FASTR + c*4]) = hiA;
    *(uint2*)(&sFA[row*FASTR + 64 + c*4]) = hiB;
    *(uint2*)(&sFA[(64 + row)*FASTR + c*4]) = loA;
    *(uint2*)(&sFA[(64 + row)*FASTR + 64 + c*4]) = loB;
  }
  __syncthreads();

  // ---- P8: gout MFMA — (quarter-mt x nt-pair): wave (mt=wv&3, ntp=wv>>2)
  // loads A for ONE mt (2 b128/ks) and reuses it for two nt (B from L2).
  // Same balance as R8's split but half the LDS A-traffic (R9-verified
  // conflict drop). ----
  {
    const int mt = wv & 3, ntp = wv >> 2;
    const int n16 = lane & 15, q = lane >> 4;
    const int h0 = ntp*32 + n16, h1 = h0 + 16;   // nt0=2*ntp, nt1=2*ntp+1
    const float bb0 = bo[h0], bb1 = bo[h1];
    const int row = mt*16 + n16;
    const u16* baseA  = &sFA[row*FASTR];
    const u16* baseAl = &sFA[(64 + row)*FASTR];
    const u16* baseB0 = ws + WOT_OFF + ((size_t)(2*ntp*KS2))*512 + lane*8;
    const u16* baseB1 = baseB0 + (size_t)KS2*512;
    v4f acc0 = {0.f, 0.f, 0.f, 0.f};
    v4f acc1 = {0.f, 0.f, 0.f, 0.f};
    #pragma unroll 2
    for (int ks = 0; ks < KS2; ++ks) {
      v8s ah = *(const v8s*)(baseA + ks*32 + q*8);
      v8s al = *(const v8s*)(baseAl + ks*32 + q*8);
      v8s bh0 = *(const v8s*)(baseB0 + ks*512);
      v8s bl0 = *(const v8s*)(baseB0 + LO_OFF + ks*512);
      v8s bh1 = *(const v8s*)(baseB1 + ks*512);
      v8s bl1 = *(const v8s*)(baseB1 + LO_OFF + ks*512);
      acc0 = __builtin_amdgcn_mfma_f32_16x16x32_bf16(ah, bh0, acc0, 0, 0, 0);
      acc0 = __builtin_amdgcn_mfma_f32_16x16x32_bf16(al, bh0, acc0, 0, 0, 0);
      acc0 = __builtin_amdgcn_mfma_f32_16x16x32_bf16(ah, bl0, acc0, 0, 0, 0);
      acc1 = __builtin_amdgcn_mfma_f32_16x16x32_bf16(ah, bh1, acc1, 0, 0, 0);
      acc1 = __builtin_amdgcn_mfma_f32_16x16x32_bf16(al, bh1, acc1, 0, 0, 0);
      acc1 = __builtin_amdgcn_mfma_f32_16x16x32_bf16(ah, bl1, acc1, 0, 0, 0);
    }
    float part0 = 0.f, part1 = 0.f;
    #pragma unroll
    for (int r = 0; r < 4; ++r) {
      int node = sSorted[mt*16 + q*4 + r];
      if (node >= 0 && sDeg[node] > 0) {
        part0 += fast_tanh(acc0[r] + bb0);
        part1 += fast_tanh(acc1[r] + bb1);
      }
    }
    part0 += __shfl_xor(part0, 16);
    part0 += __shfl_xor(part0, 32);
    part1 += __shfl_xor(part1, 16);
    part1 += __shfl_xor(part1, 32);
    if (lane < 16) {
      sPart[mt*HH + h0] = part0;
      sPart[mt*HH + h1] = part1;
    }
  }
  __syncthreads();

  // ---- P9: final FC + sigmoid (96 threads, 16 FMAs each over 4 quarters) ----
  if (t < 96) {
    const int c = t >> 3, s = t & 7;
    float acc = 0.f;
    #pragma unroll
    for (int i = 0; i < 16; ++i) {
      int ii = s*16 + i;
      float v = sPart[ii] + sPart[HH + ii] + sPart[2*HH + ii] + sPart[3*HH + ii];
      acc = fmaf(v, Wfc[ii*CC + c], acc);
    }
    sRed[t] = acc;
  }
  __syncthreads();
  if (t < CC) {
    float acc = bfc[t];
    #pragma unroll
    for (int s = 0; s < 8; ++s) acc += sRed[t*8 + s];
    out[b*CC + t] = 1.f / (1.f + __expf(-acc));
  }
}

extern "C" void kernel_launch(void* const* d_in, const int* in_sizes, int n_in,
                              void* d_out, int out_size, void* d_ws, size_t ws_size,
                              hipStream_t stream) {
  const float* atoms = (const float*)d_in[0];
  const float* bonds = (const float*)d_in[1];
  const int*   edges = (const int*)d_in[2];
  const float* W1  = (const float*)d_in[3];
  const float* b1  = (const float*)d_in[4];
  const float* W2  = (const float*)d_in[5];
  const float* b2  = (const float*)d_in[6];
  const float* Wo  = (const float*)d_in[7];
  const float* bo  = (const float*)d_in[8];
  const float* Wfc = (const float*)d_in[9];
  const float* bfc = (const float*)d_in[10];
  float* out = (float*)d_out;
  u16* ws = (u16*)d_ws;

  prep_kernel<<<(TOT_UNITS*512 + 255)/256, 256, 0, stream>>>(W1, W2, Wo, ws);
  ngfp_kernel<<<NB, T, 0, stream>>>(atoms, bonds, edges, b1, b2, bo, Wfc, bfc, ws, out);
}